// Round 3
// baseline (142.318 us; speedup 1.0000x reference)
//
#include <hip/hip_runtime.h>
#include <math.h>

#define IMG 512
#define QO  255      // qconv pooled output dim
#define QP  256      // padded row stride of qout
#define C2H 125
#define C2S 128      // padded row stride of c2out
#define C3H 123

// ---------------------------------------------------------------------------
// Register-level circuit evolution helpers (compile-time gate wiring).
// ---------------------------------------------------------------------------
template<int M_>
__device__ inline void rot_regs(float2* a, float2 U00, float2 U01, float2 U10, float2 U11) {
    #pragma unroll
    for (int s = 0; s < 16; ++s) {
        if (!(s & M_)) {
            float2 a0 = a[s], a1 = a[s | M_];
            a[s]      = make_float2(U00.x*a0.x - U00.y*a0.y + U01.x*a1.x - U01.y*a1.y,
                                    U00.x*a0.y + U00.y*a0.x + U01.x*a1.y + U01.y*a1.x);
            a[s | M_] = make_float2(U10.x*a0.x - U10.y*a0.y + U11.x*a1.x - U11.y*a1.y,
                                    U10.x*a0.y + U10.y*a0.x + U11.x*a1.y + U11.y*a1.x);
        }
    }
}
template<int MC, int MT>
__device__ inline void cnot_regs(float2* a) {
    #pragma unroll
    for (int s = 0; s < 16; ++s) {
        if ((s & MC) && !(s & MT)) {
            float2 t = a[s]; a[s] = a[s | MT]; a[s | MT] = t;
        }
    }
}
__device__ inline void rot_gate_params(float phi, float th, float om,
                                       float2& U00, float2& U01, float2& U10, float2& U11) {
    float ch, sh, ca, sa, cb, sb;
    __sincosf(0.5f * th, &sh, &ch);
    __sincosf(0.5f * (phi + om), &sa, &ca);
    __sincosf(0.5f * (phi - om), &sb, &cb);
    U00 = make_float2( ca*ch, -sa*ch);
    U01 = make_float2(-cb*sh, -sb*sh);
    U10 = make_float2( cb*sh, -sb*sh);
    U11 = make_float2( ca*ch,  sa*ch);
}

// ---------------------------------------------------------------------------
// qconv + sigmoid∘maxpool2, with the 16x16 circuit matrix built per-block
// in LDS by threads 0..15 (register evolution, no extra kernel).
// 2 threads per pooled pixel: parity p owns patch-row p (2 patches),
// pair-combined via shfl_xor. out: [4][QP][QP] padded.
// ---------------------------------------------------------------------------
__global__ __launch_bounds__(256) void qconv_pool(const float* __restrict__ img,
                                                  const float* __restrict__ qw,
                                                  float* __restrict__ out) {
    __shared__ float2 Ms[256];
    int tid = threadIdx.x;

    if (tid < 16) {
        float2 a[16];
        #pragma unroll
        for (int s = 0; s < 16; ++s) a[s] = make_float2(s == tid ? 1.f : 0.f, 0.f);
        float2 U00, U01, U10, U11;
#define ROTG(L, W) rot_gate_params(qw[((L)*4+(W))*3+0], qw[((L)*4+(W))*3+1], qw[((L)*4+(W))*3+2], U00,U01,U10,U11); \
                   rot_regs<(1 << (3-(W)))>(a, U00, U01, U10, U11);
        ROTG(0,0) ROTG(0,1) ROTG(0,2) ROTG(0,3)
        cnot_regs<8,4>(a); cnot_regs<4,2>(a); cnot_regs<2,1>(a); cnot_regs<1,8>(a);
        ROTG(1,0) ROTG(1,1) ROTG(1,2) ROTG(1,3)
        cnot_regs<8,2>(a); cnot_regs<4,1>(a); cnot_regs<2,8>(a); cnot_regs<1,4>(a);
        ROTG(2,0) ROTG(2,1) ROTG(2,2) ROTG(2,3)
        cnot_regs<8,1>(a); cnot_regs<4,8>(a); cnot_regs<2,4>(a); cnot_regs<1,2>(a);
#undef ROTG
        int pc4 = __popc(tid) & 3;
        #pragma unroll
        for (int row = 0; row < 16; ++row) {
            float2 v = a[row], o;
            if      (pc4 == 0) o = v;
            else if (pc4 == 1) o = make_float2( v.y, -v.x);   // * (-i)
            else if (pc4 == 2) o = make_float2(-v.x, -v.y);   // * (-1)
            else               o = make_float2(-v.y,  v.x);   // * (+i)
            Ms[row * 16 + tid] = o;
        }
    }
    __syncthreads();

    int gid = blockIdx.x * 256 + tid;
    int pid = gid >> 1, p = gid & 1;
    if (pid >= QO * QO) return;
    int i = pid / QO, j = pid - i * QO;
    int r0 = 2 * i + p, c0 = 2 * j;

    float cs[2][3], sn[2][3];
    #pragma unroll
    for (int rr = 0; rr < 2; ++rr)
        #pragma unroll
        for (int cc = 0; cc < 3; ++cc) {
            float v = img[(r0 + rr) * IMG + c0 + cc];
            __sincosf(0.5f * v, &sn[rr][cc], &cs[rr][cc]);
        }

    float mx0 = -1e30f, mx1 = -1e30f, mx2 = -1e30f, mx3 = -1e30f;

    #pragma unroll
    for (int pc = 0; pc < 2; ++pc) {
        float c0v = cs[0][pc],   s0 = sn[0][pc];
        float c1v = cs[0][pc+1], s1 = sn[0][pc+1];
        float c2v = cs[1][pc],   s2 = sn[1][pc];
        float c3v = cs[1][pc+1], s3 = sn[1][pc+1];
        float t01[4] = {c0v*c1v, c0v*s1, s0*c1v, s0*s1};
        float t23[4] = {c2v*c3v, c2v*s3, s2*c3v, s2*s3};
        float a[16];
        #pragma unroll
        for (int k = 0; k < 16; ++k) a[k] = t01[k >> 2] * t23[k & 3];

        float e0 = 0.f, e1 = 0.f, e2 = 0.f, e3 = 0.f;
        #pragma unroll 4
        for (int rw = 0; rw < 16; ++rw) {
            float re = 0.f, im = 0.f;
            #pragma unroll
            for (int k = 0; k < 16; ++k) {
                float2 m = Ms[rw * 16 + k];   // uniform LDS broadcast
                re = fmaf(m.x, a[k], re);
                im = fmaf(m.y, a[k], im);
            }
            float pp = fmaf(re, re, im * im);
            e0 += (rw & 8) ? -pp : pp;
            e1 += (rw & 4) ? -pp : pp;
            e2 += (rw & 2) ? -pp : pp;
            e3 += (rw & 1) ? -pp : pp;
        }
        mx0 = fmaxf(mx0, e0);
        mx1 = fmaxf(mx1, e1);
        mx2 = fmaxf(mx2, e2);
        mx3 = fmaxf(mx3, e3);
    }

    // combine the two patch-rows of this pooled pixel (lanes 2k / 2k+1)
    mx0 = fmaxf(mx0, __shfl_xor(mx0, 1, 64));
    mx1 = fmaxf(mx1, __shfl_xor(mx1, 1, 64));
    mx2 = fmaxf(mx2, __shfl_xor(mx2, 1, 64));
    mx3 = fmaxf(mx3, __shfl_xor(mx3, 1, 64));

    if (p == 0) {
        int o = i * QP + j;
        out[0 * QP * QP + o] = 1.f / (1.f + __expf(-mx0));
        out[1 * QP * QP + o] = 1.f / (1.f + __expf(-mx1));
        out[2 * QP * QP + o] = 1.f / (1.f + __expf(-mx2));
        out[3 * QP * QP + o] = 1.f / (1.f + __expf(-mx3));
    }
}

// ---------------------------------------------------------------------------
// conv2 (4->20, 5x5) + bias + relu + maxpool2. oc = blockIdx.y (uniform
// weights -> scalar loads). Also zero-inits the 640 adaptive-max bins.
// ---------------------------------------------------------------------------
__global__ __launch_bounds__(256) void conv2_pool(const float* __restrict__ in,
                                                  const float* __restrict__ w,
                                                  const float* __restrict__ b,
                                                  float* __restrict__ out,
                                                  float* __restrict__ am) {
    if (blockIdx.x == 0 && blockIdx.y == 0) {
        for (int e = threadIdx.x; e < 640; e += 256) am[e] = 0.f;
    }
    int oc = blockIdx.y;
    int sp = blockIdx.x * 256 + threadIdx.x;
    if (sp >= C2H * C2H) return;
    int i = sp / C2H, j = sp - i * C2H;
    const float* wb = w + oc * 100;

    float a00 = 0.f, a01 = 0.f, a10 = 0.f, a11 = 0.f;
    #pragma unroll
    for (int ic = 0; ic < 4; ++ic) {
        const float* ip = in + ic * QP * QP + (2 * i) * QP + 2 * j;
        float win[6][6];
        #pragma unroll
        for (int y = 0; y < 6; ++y) {
            #pragma unroll
            for (int h = 0; h < 3; ++h) {
                float2 v = *(const float2*)(ip + y * QP + 2 * h);
                win[y][2*h]   = v.x;
                win[y][2*h+1] = v.y;
            }
        }
        #pragma unroll
        for (int ky = 0; ky < 5; ++ky) {
            #pragma unroll
            for (int kx = 0; kx < 5; ++kx) {
                float wv = wb[ic * 25 + ky * 5 + kx];   // uniform -> s_load
                a00 = fmaf(win[ky][kx],     wv, a00);
                a01 = fmaf(win[ky][kx+1],   wv, a01);
                a10 = fmaf(win[ky+1][kx],   wv, a10);
                a11 = fmaf(win[ky+1][kx+1], wv, a11);
            }
        }
    }
    float m = fmaxf(fmaxf(a00, a01), fmaxf(a10, a11));
    out[oc * C2H * C2S + i * C2S + j] = fmaxf(m + b[oc], 0.f);
}

// ---------------------------------------------------------------------------
// conv3 (20->40, 3x3) + bias + relu fused with adaptive-max-4x4 reduction.
// No conv3 output tensor: LDS per-block max bins -> global atomicMax.
// Float-as-int atomicMax is order-preserving for the non-negative relu output.
// ---------------------------------------------------------------------------
__global__ __launch_bounds__(256) void conv3_amax(const float* __restrict__ in,
                                                  const float* __restrict__ w,
                                                  const float* __restrict__ b,
                                                  int* __restrict__ am) {
    __shared__ int bm[64];   // [ocl 0..3][bin 0..15]
    int og = blockIdx.y, oc0 = og * 4;
    if (threadIdx.x < 64) bm[threadIdx.x] = 0;
    __syncthreads();

    int sp = blockIdx.x * 256 + threadIdx.x;
    if (sp < C3H * C3H) {
        int y = sp / C3H, x = sp - y * C3H;
        const float* wb = w + oc0 * 180;

        float acc0 = 0.f, acc1 = 0.f, acc2 = 0.f, acc3 = 0.f;
        #pragma unroll
        for (int ic = 0; ic < 20; ++ic) {
            const float* ip = in + ic * C2H * C2S + y * C2S + x;
            float v[3][3];
            #pragma unroll
            for (int ky = 0; ky < 3; ++ky)
                #pragma unroll
                for (int kx = 0; kx < 3; ++kx)
                    v[ky][kx] = ip[ky * C2S + kx];
            #pragma unroll
            for (int kk = 0; kk < 9; ++kk) {
                float iv = v[kk / 3][kk % 3];
                acc0 = fmaf(iv, wb[      ic * 9 + kk], acc0);  // uniform
                acc1 = fmaf(iv, wb[180 + ic * 9 + kk], acc1);
                acc2 = fmaf(iv, wb[360 + ic * 9 + kk], acc2);
                acc3 = fmaf(iv, wb[540 + ic * 9 + kk], acc3);
            }
        }
        acc0 = fmaxf(acc0 + b[oc0 + 0], 0.f);
        acc1 = fmaxf(acc1 + b[oc0 + 1], 0.f);
        acc2 = fmaxf(acc2 + b[oc0 + 2], 0.f);
        acc3 = fmaxf(acc3 + b[oc0 + 3], 0.f);

        // adaptive bins: start i*123//4 = {0,30,61,92}, end ceil = {31,62,93,123}
        const int bs[4] = {0, 30, 61, 92};
        const int be[4] = {31, 62, 93, 123};
        #pragma unroll
        for (int yb = 0; yb < 4; ++yb) {
            if (y >= bs[yb] && y < be[yb]) {
                #pragma unroll
                for (int xb = 0; xb < 4; ++xb) {
                    if (x >= bs[xb] && x < be[xb]) {
                        int bin = yb * 4 + xb;
                        atomicMax(&bm[0 * 16 + bin], __float_as_int(acc0));
                        atomicMax(&bm[1 * 16 + bin], __float_as_int(acc1));
                        atomicMax(&bm[2 * 16 + bin], __float_as_int(acc2));
                        atomicMax(&bm[3 * 16 + bin], __float_as_int(acc3));
                    }
                }
            }
        }
    }
    __syncthreads();
    if (threadIdx.x < 64) {
        int v = bm[threadIdx.x];
        if (v != 0)
            atomicMax(&am[(oc0 + (threadIdx.x >> 4)) * 16 + (threadIdx.x & 15)], v);
    }
}

// ---------------------------------------------------------------------------
// fc1 (640->64) + relu + fc2 (64->10). 256 threads: 4 lanes per fc1 row.
// ---------------------------------------------------------------------------
__global__ void fc_k(const float* __restrict__ h, const float* __restrict__ w1,
                     const float* __restrict__ b1, const float* __restrict__ w2,
                     const float* __restrict__ b2, float* __restrict__ out) {
    __shared__ float hh[640];
    __shared__ float h1[64];
    int t = threadIdx.x;   // 256
    for (int e = t; e < 640; e += 256) hh[e] = h[e];
    __syncthreads();

    int r = t >> 2, q = t & 3;
    const float4* wr = (const float4*)(w1 + r * 640 + q * 160);
    const float*  hp = hh + q * 160;
    float acc = 0.f;
    #pragma unroll 4
    for (int n = 0; n < 40; ++n) {
        float4 wv = wr[n];
        acc = fmaf(wv.x, hp[n*4+0], acc);
        acc = fmaf(wv.y, hp[n*4+1], acc);
        acc = fmaf(wv.z, hp[n*4+2], acc);
        acc = fmaf(wv.w, hp[n*4+3], acc);
    }
    acc += __shfl_xor(acc, 1, 64);
    acc += __shfl_xor(acc, 2, 64);
    if (q == 0) h1[r] = fmaxf(acc + b1[r], 0.f);
    __syncthreads();

    if (t < 10) {
        float o = b2[t];
        #pragma unroll 8
        for (int n = 0; n < 64; ++n) o = fmaf(h1[n], w2[t * 64 + n], o);
        out[t] = o;
    }
}

// ---------------------------------------------------------------------------
extern "C" void kernel_launch(void* const* d_in, const int* in_sizes, int n_in,
                              void* d_out, int out_size, void* d_ws, size_t ws_size,
                              hipStream_t stream) {
    const float* x   = (const float*)d_in[0];
    const float* qw  = (const float*)d_in[1];
    const float* c2w = (const float*)d_in[2];
    const float* c2b = (const float*)d_in[3];
    const float* c3w = (const float*)d_in[4];
    const float* c3b = (const float*)d_in[5];
    const float* f1w = (const float*)d_in[6];
    const float* f1b = (const float*)d_in[7];
    const float* f2w = (const float*)d_in[8];
    const float* f2b = (const float*)d_in[9];
    float* out = (float*)d_out;

    float* wsf   = (float*)d_ws;
    float* qout  = wsf;                              // [4][256][256]   1 MB
    float* c2out = qout + 4 * QP * QP;               // [20][125][128]  1.28 MB
    float* am    = c2out + 20 * C2H * C2S;           // 640 floats

    qconv_pool<<<(2 * QO * QO + 255) / 256, 256, 0, stream>>>(x, qw, qout);
    conv2_pool<<<dim3((C2H * C2H + 255) / 256, 20), 256, 0, stream>>>(qout, c2w, c2b, c2out, am);
    conv3_amax<<<dim3((C3H * C3H + 255) / 256, 10), 256, 0, stream>>>(c2out, c3w, c3b, (int*)am);
    fc_k<<<1, 256, 0, stream>>>(am, f1w, f1b, f2w, f2b, out);
}

// Round 4
// 134.514 us; speedup vs baseline: 1.0580x; 1.0580x over previous
//
#include <hip/hip_runtime.h>
#include <math.h>

#define IMG 512
#define QO  255      // qconv pooled output dim
#define QP  256      // padded row stride of qout
#define C2H 125
#define C2S 128      // padded row stride of c2out
#define C3H 123

// ---------------------------------------------------------------------------
// Register-level circuit evolution helpers (compile-time gate wiring).
// ---------------------------------------------------------------------------
template<int M_>
__device__ inline void rot_regs(float2* a, float2 U00, float2 U01, float2 U10, float2 U11) {
    #pragma unroll
    for (int s = 0; s < 16; ++s) {
        if (!(s & M_)) {
            float2 a0 = a[s], a1 = a[s | M_];
            a[s]      = make_float2(U00.x*a0.x - U00.y*a0.y + U01.x*a1.x - U01.y*a1.y,
                                    U00.x*a0.y + U00.y*a0.x + U01.x*a1.y + U01.y*a1.x);
            a[s | M_] = make_float2(U10.x*a0.x - U10.y*a0.y + U11.x*a1.x - U11.y*a1.y,
                                    U10.x*a0.y + U10.y*a0.x + U11.x*a1.y + U11.y*a1.x);
        }
    }
}
template<int MC, int MT>
__device__ inline void cnot_regs(float2* a) {
    #pragma unroll
    for (int s = 0; s < 16; ++s) {
        if ((s & MC) && !(s & MT)) {
            float2 t = a[s]; a[s] = a[s | MT]; a[s | MT] = t;
        }
    }
}
__device__ inline void rot_gate_params(float phi, float th, float om,
                                       float2& U00, float2& U01, float2& U10, float2& U11) {
    float ch, sh, ca, sa, cb, sb;
    __sincosf(0.5f * th, &sh, &ch);
    __sincosf(0.5f * (phi + om), &sa, &ca);
    __sincosf(0.5f * (phi - om), &sb, &cb);
    U00 = make_float2( ca*ch, -sa*ch);
    U01 = make_float2(-cb*sh, -sb*sh);
    U10 = make_float2( cb*sh, -sb*sh);
    U11 = make_float2( ca*ch,  sa*ch);
}

// sym-pair tables for 4-vectors: index alpha -> (U1[alpha], U2[alpha])
__device__ __constant__ int UP1[10] = {0,0,0,0,1,1,1,2,2,3};
__device__ __constant__ int UP2[10] = {0,1,2,3,1,2,3,2,3,3};

// ---------------------------------------------------------------------------
// qconv + sigmoid∘maxpool2 via the bilinear form:
//   ez_w(patch) = sum_{alpha,beta} Ghat_w[alpha][beta] * Q01[alpha] * Q23[beta]
// where Q01/Q23 are the 10 distinct entries of t01*t01^T / t23*t23^T and
// Ghat folds M^H D_w M (built per block in LDS from the register-evolved M).
// One thread per pooled pixel. out: [4][QP][QP] padded.
// ---------------------------------------------------------------------------
__global__ __launch_bounds__(256) void qconv_pool(const float* __restrict__ img,
                                                  const float* __restrict__ qw,
                                                  float* __restrict__ out) {
    __shared__ float2 Ms[256];
    __shared__ float4 G4[100];
    int tid = threadIdx.x;

    // ---- stage 1: threads 0..15 build phase-folded M into LDS ----
    if (tid < 16) {
        float2 a[16];
        #pragma unroll
        for (int s = 0; s < 16; ++s) a[s] = make_float2(s == tid ? 1.f : 0.f, 0.f);
        float2 U00, U01, U10, U11;
#define ROTG(L, W) rot_gate_params(qw[((L)*4+(W))*3+0], qw[((L)*4+(W))*3+1], qw[((L)*4+(W))*3+2], U00,U01,U10,U11); \
                   rot_regs<(1 << (3-(W)))>(a, U00, U01, U10, U11);
        ROTG(0,0) ROTG(0,1) ROTG(0,2) ROTG(0,3)
        cnot_regs<8,4>(a); cnot_regs<4,2>(a); cnot_regs<2,1>(a); cnot_regs<1,8>(a);
        ROTG(1,0) ROTG(1,1) ROTG(1,2) ROTG(1,3)
        cnot_regs<8,2>(a); cnot_regs<4,1>(a); cnot_regs<2,8>(a); cnot_regs<1,4>(a);
        ROTG(2,0) ROTG(2,1) ROTG(2,2) ROTG(2,3)
        cnot_regs<8,1>(a); cnot_regs<4,8>(a); cnot_regs<2,4>(a); cnot_regs<1,2>(a);
#undef ROTG
        int pc4 = __popc(tid) & 3;
        #pragma unroll
        for (int row = 0; row < 16; ++row) {
            float2 v = a[row], o;
            if      (pc4 == 0) o = v;
            else if (pc4 == 1) o = make_float2( v.y, -v.x);   // * (-i)
            else if (pc4 == 2) o = make_float2(-v.x, -v.y);   // * (-1)
            else               o = make_float2(-v.y,  v.x);   // * (+i)
            Ms[row * 16 + tid] = o;
        }
    }
    __syncthreads();

    // ---- stage 2: threads 0..99 build Ghat[alpha][beta] (float4 over w) ----
    if (tid < 100) {
        int al = tid / 10, be = tid - 10 * (tid / 10);
        int u = UP1[al], up = UP2[al], v = UP1[be], vp = UP2[be];
        float s0 = 0.f, s1 = 0.f, s2 = 0.f, s3 = 0.f;
        for (int ci = 0; ci < 2; ++ci) {
            if (ci == 1 && u == up) break;
            int a1 = ci ? up : u, a2 = ci ? u : up;
            for (int cj = 0; cj < 2; ++cj) {
                if (cj == 1 && v == vp) break;
                int b1 = cj ? vp : v, b2 = cj ? v : vp;
                int k = a1 * 4 + b1, kp = a2 * 4 + b2;
                #pragma unroll
                for (int r = 0; r < 16; ++r) {
                    float2 m1 = Ms[r * 16 + k], m2 = Ms[r * 16 + kp];
                    float p = m1.x * m2.x + m1.y * m2.y;
                    s0 += (r & 8) ? -p : p;
                    s1 += (r & 4) ? -p : p;
                    s2 += (r & 2) ? -p : p;
                    s3 += (r & 1) ? -p : p;
                }
            }
        }
        G4[tid] = make_float4(s0, s1, s2, s3);
    }
    __syncthreads();

    // ---- stage 3: per pooled pixel ----
    int gid = blockIdx.x * 256 + tid;
    if (gid >= QO * QO) return;
    int i = gid / QO, j = gid - i * QO;
    int r0 = 2 * i, c0 = 2 * j;

    float cs[3][3], sn[3][3];
    #pragma unroll
    for (int rr = 0; rr < 3; ++rr)
        #pragma unroll
        for (int cc = 0; cc < 3; ++cc) {
            float v = img[(r0 + rr) * IMG + c0 + cc];
            __sincosf(0.5f * v, &sn[rr][cc], &cs[rr][cc]);
        }

    // horizontal-pair product vectors t[row][pc][4]
    float tv[3][2][4];
    #pragma unroll
    for (int rr = 0; rr < 3; ++rr)
        #pragma unroll
        for (int pc = 0; pc < 2; ++pc) {
            tv[rr][pc][0] = cs[rr][pc] * cs[rr][pc+1];
            tv[rr][pc][1] = cs[rr][pc] * sn[rr][pc+1];
            tv[rr][pc][2] = sn[rr][pc] * cs[rr][pc+1];
            tv[rr][pc][3] = sn[rr][pc] * sn[rr][pc+1];
        }

    float mx0 = -1e30f, mx1 = -1e30f, mx2 = -1e30f, mx3 = -1e30f;

    #pragma unroll
    for (int pr = 0; pr < 2; ++pr) {
        #pragma unroll
        for (int pc = 0; pc < 2; ++pc) {
            float q23[10];
            #pragma unroll
            for (int be = 0; be < 10; ++be)
                q23[be] = tv[pr+1][pc][UP1[be]] * tv[pr+1][pc][UP2[be]];

            float e0 = 0.f, e1 = 0.f, e2 = 0.f, e3 = 0.f;
            #pragma unroll
            for (int al = 0; al < 10; ++al) {
                float pa = tv[pr][pc][UP1[al]] * tv[pr][pc][UP2[al]];
                #pragma unroll
                for (int be = 0; be < 10; ++be) {
                    float4 g = G4[al * 10 + be];    // uniform LDS broadcast
                    float pq = pa * q23[be];
                    e0 = fmaf(g.x, pq, e0);
                    e1 = fmaf(g.y, pq, e1);
                    e2 = fmaf(g.z, pq, e2);
                    e3 = fmaf(g.w, pq, e3);
                }
            }
            mx0 = fmaxf(mx0, e0);
            mx1 = fmaxf(mx1, e1);
            mx2 = fmaxf(mx2, e2);
            mx3 = fmaxf(mx3, e3);
        }
    }

    int o = i * QP + j;
    out[0 * QP * QP + o] = 1.f / (1.f + __expf(-mx0));
    out[1 * QP * QP + o] = 1.f / (1.f + __expf(-mx1));
    out[2 * QP * QP + o] = 1.f / (1.f + __expf(-mx2));
    out[3 * QP * QP + o] = 1.f / (1.f + __expf(-mx3));
}

// ---------------------------------------------------------------------------
// conv2 (4->20, 5x5) + bias + relu + maxpool2. oc = blockIdx.y; that oc's 100
// weights staged in LDS (broadcast reads). Zero-inits the adaptive-max bins.
// ---------------------------------------------------------------------------
__global__ __launch_bounds__(256) void conv2_pool(const float* __restrict__ in,
                                                  const float* __restrict__ w,
                                                  const float* __restrict__ b,
                                                  float* __restrict__ out,
                                                  float* __restrict__ am) {
    __shared__ float W[100];
    __shared__ float Bv;
    int oc = blockIdx.y;
    if (threadIdx.x < 100) W[threadIdx.x] = w[oc * 100 + threadIdx.x];
    if (threadIdx.x == 0) Bv = b[oc];
    if (blockIdx.x == 0 && oc == 0) {
        for (int e = threadIdx.x; e < 640; e += 256) am[e] = 0.f;
    }
    __syncthreads();

    int sp = blockIdx.x * 256 + threadIdx.x;
    if (sp >= C2H * C2H) return;
    int i = sp / C2H, j = sp - i * C2H;

    float a00 = 0.f, a01 = 0.f, a10 = 0.f, a11 = 0.f;
    #pragma unroll
    for (int ic = 0; ic < 4; ++ic) {
        const float* ip = in + ic * QP * QP + (2 * i) * QP + 2 * j;
        float win[6][6];
        #pragma unroll
        for (int y = 0; y < 6; ++y) {
            #pragma unroll
            for (int h = 0; h < 3; ++h) {
                float2 v = *(const float2*)(ip + y * QP + 2 * h);
                win[y][2*h]   = v.x;
                win[y][2*h+1] = v.y;
            }
        }
        #pragma unroll
        for (int ky = 0; ky < 5; ++ky) {
            #pragma unroll
            for (int kx = 0; kx < 5; ++kx) {
                float wv = W[ic * 25 + ky * 5 + kx];   // LDS broadcast
                a00 = fmaf(win[ky][kx],     wv, a00);
                a01 = fmaf(win[ky][kx+1],   wv, a01);
                a10 = fmaf(win[ky+1][kx],   wv, a10);
                a11 = fmaf(win[ky+1][kx+1], wv, a11);
            }
        }
    }
    float m = fmaxf(fmaxf(a00, a01), fmaxf(a10, a11));
    out[oc * C2H * C2S + i * C2S + j] = fmaxf(m + Bv, 0.f);
}

// ---------------------------------------------------------------------------
// conv3 (20->40, 3x3) + bias + relu fused with adaptive-max-4x4.
// og = blockIdx.y owns 4 output channels; weights packed float4 in LDS.
// LDS per-block bins -> device atomicMax (float-as-int, valid for relu >= 0).
// ---------------------------------------------------------------------------
__global__ __launch_bounds__(256) void conv3_amax(const float* __restrict__ in,
                                                  const float* __restrict__ w,
                                                  const float* __restrict__ b,
                                                  int* __restrict__ am) {
    __shared__ float4 W4[180];
    __shared__ int bm[64];   // [ocl 0..3][bin 0..15]
    int og = blockIdx.y, oc0 = og * 4;
    if (threadIdx.x < 180) {
        int rr = threadIdx.x;
        const float* wb = w + oc0 * 180 + rr;
        W4[rr] = make_float4(wb[0], wb[180], wb[360], wb[540]);
    }
    if (threadIdx.x < 64) bm[threadIdx.x] = 0;
    __syncthreads();

    int sp = blockIdx.x * 256 + threadIdx.x;
    if (sp < C3H * C3H) {
        int y = sp / C3H, x = sp - y * C3H;

        float acc0 = 0.f, acc1 = 0.f, acc2 = 0.f, acc3 = 0.f;
        #pragma unroll
        for (int ic = 0; ic < 20; ++ic) {
            const float* ip = in + ic * C2H * C2S + y * C2S + x;
            float v[3][3];
            #pragma unroll
            for (int ky = 0; ky < 3; ++ky)
                #pragma unroll
                for (int kx = 0; kx < 3; ++kx)
                    v[ky][kx] = ip[ky * C2S + kx];
            #pragma unroll
            for (int kk = 0; kk < 9; ++kk) {
                float4 wv = W4[ic * 9 + kk];        // LDS broadcast
                float iv = v[kk / 3][kk % 3];
                acc0 = fmaf(iv, wv.x, acc0);
                acc1 = fmaf(iv, wv.y, acc1);
                acc2 = fmaf(iv, wv.z, acc2);
                acc3 = fmaf(iv, wv.w, acc3);
            }
        }
        acc0 = fmaxf(acc0 + b[oc0 + 0], 0.f);
        acc1 = fmaxf(acc1 + b[oc0 + 1], 0.f);
        acc2 = fmaxf(acc2 + b[oc0 + 2], 0.f);
        acc3 = fmaxf(acc3 + b[oc0 + 3], 0.f);

        // adaptive bins: start {0,30,61,92}, end {31,62,93,123} (overlapping)
        const int bs[4] = {0, 30, 61, 92};
        const int be[4] = {31, 62, 93, 123};
        #pragma unroll
        for (int yb = 0; yb < 4; ++yb) {
            if (y >= bs[yb] && y < be[yb]) {
                #pragma unroll
                for (int xb = 0; xb < 4; ++xb) {
                    if (x >= bs[xb] && x < be[xb]) {
                        int bin = yb * 4 + xb;
                        atomicMax(&bm[0 * 16 + bin], __float_as_int(acc0));
                        atomicMax(&bm[1 * 16 + bin], __float_as_int(acc1));
                        atomicMax(&bm[2 * 16 + bin], __float_as_int(acc2));
                        atomicMax(&bm[3 * 16 + bin], __float_as_int(acc3));
                    }
                }
            }
        }
    }
    __syncthreads();
    if (threadIdx.x < 64) {
        int v = bm[threadIdx.x];
        if (v != 0)
            atomicMax(&am[(oc0 + (threadIdx.x >> 4)) * 16 + (threadIdx.x & 15)], v);
    }
}

// ---------------------------------------------------------------------------
// fc1 (640->64) + relu + fc2 (64->10). 256 threads: 4 lanes per fc1 row.
// ---------------------------------------------------------------------------
__global__ void fc_k(const float* __restrict__ h, const float* __restrict__ w1,
                     const float* __restrict__ b1, const float* __restrict__ w2,
                     const float* __restrict__ b2, float* __restrict__ out) {
    __shared__ float hh[640];
    __shared__ float h1[64];
    int t = threadIdx.x;   // 256
    for (int e = t; e < 640; e += 256) hh[e] = h[e];
    __syncthreads();

    int r = t >> 2, q = t & 3;
    const float4* wr = (const float4*)(w1 + r * 640 + q * 160);
    const float*  hp = hh + q * 160;
    float acc = 0.f;
    #pragma unroll 4
    for (int n = 0; n < 40; ++n) {
        float4 wv = wr[n];
        acc = fmaf(wv.x, hp[n*4+0], acc);
        acc = fmaf(wv.y, hp[n*4+1], acc);
        acc = fmaf(wv.z, hp[n*4+2], acc);
        acc = fmaf(wv.w, hp[n*4+3], acc);
    }
    acc += __shfl_xor(acc, 1, 64);
    acc += __shfl_xor(acc, 2, 64);
    if (q == 0) h1[r] = fmaxf(acc + b1[r], 0.f);
    __syncthreads();

    if (t < 10) {
        float o = b2[t];
        #pragma unroll 8
        for (int n = 0; n < 64; ++n) o = fmaf(h1[n], w2[t * 64 + n], o);
        out[t] = o;
    }
}

// ---------------------------------------------------------------------------
extern "C" void kernel_launch(void* const* d_in, const int* in_sizes, int n_in,
                              void* d_out, int out_size, void* d_ws, size_t ws_size,
                              hipStream_t stream) {
    const float* x   = (const float*)d_in[0];
    const float* qw  = (const float*)d_in[1];
    const float* c2w = (const float*)d_in[2];
    const float* c2b = (const float*)d_in[3];
    const float* c3w = (const float*)d_in[4];
    const float* c3b = (const float*)d_in[5];
    const float* f1w = (const float*)d_in[6];
    const float* f1b = (const float*)d_in[7];
    const float* f2w = (const float*)d_in[8];
    const float* f2b = (const float*)d_in[9];
    float* out = (float*)d_out;

    float* wsf   = (float*)d_ws;
    float* qout  = wsf;                              // [4][256][256]   1 MB
    float* c2out = qout + 4 * QP * QP;               // [20][125][128]  1.28 MB
    float* am    = c2out + 20 * C2H * C2S;           // 640 floats

    qconv_pool<<<(QO * QO + 255) / 256, 256, 0, stream>>>(x, qw, qout);
    conv2_pool<<<dim3((C2H * C2H + 255) / 256, 20), 256, 0, stream>>>(qout, c2w, c2b, c2out, am);
    conv3_amax<<<dim3((C3H * C3H + 255) / 256, 10), 256, 0, stream>>>(c2out, c3w, c3b, (int*)am);
    fc_k<<<1, 256, 0, stream>>>(am, f1w, f1b, f2w, f2b, out);
}